// Round 1
// baseline (4003.496 us; speedup 1.0000x reference)
//
#include <hip/hip_runtime.h>

#define NN 100000
#define EC 6400000
#define ED 400000
#define BN_EPS 1e-5f

// ---------------- CSR build ----------------

__global__ void count_deg(const int* __restrict__ eic, const int* __restrict__ eid,
                          int* __restrict__ deg_ic, int* __restrict__ deg_id) {
    int t = blockIdx.x * blockDim.x + threadIdx.x;
    int stride = gridDim.x * blockDim.x;
    for (int e = t; e < EC; e += stride) atomicAdd(&deg_ic[eic[EC + e]], 1);
    for (int e = t; e < ED; e += stride) atomicAdd(&deg_id[eid[ED + e]], 1);
}

// per-wave exclusive scan of degrees + one global-cursor atomic per wave
__global__ void make_offs(const int* __restrict__ deg, int* __restrict__ offs,
                          int* __restrict__ cur, float* __restrict__ inv,
                          int* __restrict__ gcnt) {
    int t = blockIdx.x * blockDim.x + threadIdx.x;
    int lane = threadIdx.x & 63;
    int d = (t < NN) ? deg[t] : 0;
    int x = d;
    #pragma unroll
    for (int s = 1; s < 64; s <<= 1) {
        int y = __shfl_up(x, s);
        if (lane >= s) x += y;
    }
    int total = __shfl(x, 63);           // wave total (inclusive scan at lane 63)
    int base = 0;
    if (lane == 0) base = atomicAdd(gcnt, total);
    base = __shfl(base, 0);
    if (t < NN) {
        int o = base + (x - d);          // exclusive within wave
        offs[t] = o;
        cur[t]  = o;
        inv[t]  = 1.0f / (float)(d > 1 ? d : 1);
    }
}

__global__ void fill_csr(const int* __restrict__ ei, int E,
                         int* __restrict__ cur, int* __restrict__ csr) {
    int t = blockIdx.x * blockDim.x + threadIdx.x;
    int stride = gridDim.x * blockDim.x;
    for (int e = t; e < E; e += stride) {
        int src = ei[e];
        int dst = ei[E + e];
        int p = atomicAdd(&cur[dst], 1);
        csr[p] = src;
    }
}

// ---------------- fused SAGE layer ----------------
// One wave per node. Lane = e8*8 + f : 8 parallel edges x 8 features.
// Input activations are RAW (pre-BN) relu outputs of the previous layer;
// the previous layer's BN affine (from its batch stats) is applied inline.
// Output: raw relu of L2-normalized SAGE output, plus BN stat accumulation.
template<int FIN_, bool APPLY_BN>
__global__ __launch_bounds__(256)
void sage_layer(const float* __restrict__ hin,
                const float* __restrict__ stats_in,   // [16] sum, sumsq (prev layer)
                const float* __restrict__ gin, const float* __restrict__ bin,
                const int* __restrict__ offs, const int* __restrict__ deg,
                const int* __restrict__ csr, const float* __restrict__ inv,
                const float* __restrict__ Wl, const float* __restrict__ Wr,
                float* __restrict__ hout,
                float* __restrict__ stats_out) {
    __shared__ float bl[16];
    int tid = threadIdx.x;
    if (tid < 16) bl[tid] = 0.f;
    __syncthreads();

    int wave = tid >> 6;
    int lane = tid & 63;
    int e8 = lane >> 3;
    int f  = lane & 7;
    int i = blockIdx.x * 4 + wave;       // node index

    float sc = 1.f, sh = 0.f;
    if constexpr (APPLY_BN) {
        float m = stats_in[f] * (1.0f / NN);
        float v = stats_in[8 + f] * (1.0f / NN) - m * m;
        float is = rsqrtf(v + BN_EPS);
        sc = gin[f] * is;
        sh = bin[f] - m * sc;
    }

    float r = 0.f;
    if (i < NN) {
        int d = deg[i];
        int o = offs[i];
        bool actf = (f < FIN_);
        float s = 0.f;
        for (int j = e8; j < d; j += 8) {
            int src = csr[o + j];
            float v = 0.f;
            if (actf) {
                v = hin[src * FIN_ + f];
                if constexpr (APPLY_BN) v = fmaf(v, sc, sh);
            }
            s += v;
        }
        // reduce over the 8 edge slots (lanes differing in bits 3..5)
        s += __shfl_xor(s, 8);
        s += __shfl_xor(s, 16);
        s += __shfl_xor(s, 32);
        float meanf = s * inv[i];

        float hf = 0.f;
        if (f < FIN_) {
            hf = hin[i * FIN_ + f];
            if constexpr (APPLY_BN) hf = fmaf(hf, sc, sh);
        }

        // y_f = sum_k mean_k*Wl[f][k] + h_k*Wr[f][k]   (shuffle within 8-lane group)
        float y = 0.f;
        int gbase = lane & ~7;
        #pragma unroll
        for (int k = 0; k < FIN_; ++k) {
            float mk = __shfl(meanf, gbase + k);
            float hk = __shfl(hf, gbase + k);
            y = fmaf(mk, Wl[f * FIN_ + k], y);
            y = fmaf(hk, Wr[f * FIN_ + k], y);
        }
        // row L2 norm over 8 features (lanes differing in bits 0..2)
        float n2 = y * y;
        n2 += __shfl_xor(n2, 1);
        n2 += __shfl_xor(n2, 2);
        n2 += __shfl_xor(n2, 4);
        float z = y / fmaxf(sqrtf(n2), 1e-12f);
        r = fmaxf(z, 0.f);
        if (e8 == 0) hout[i * 8 + f] = r;
    }

    if (e8 == 0 && i < NN) {
        atomicAdd(&bl[f], r);
        atomicAdd(&bl[8 + f], r * r);
    }
    __syncthreads();
    if (tid < 16) atomicAdd(&stats_out[tid], bl[tid]);
}

__global__ void apply_bn_out(const float* __restrict__ hin,
                             const float* __restrict__ stats,
                             const float* __restrict__ g, const float* __restrict__ b,
                             float* __restrict__ out) {
    int t = blockIdx.x * blockDim.x + threadIdx.x;
    if (t >= NN * 8) return;
    int f = t & 7;
    float m = stats[f] * (1.0f / NN);
    float v = stats[8 + f] * (1.0f / NN) - m * m;
    float sc = g[f] * rsqrtf(v + BN_EPS);
    float sh = b[f] - m * sc;
    out[t] = fmaf(hin[t], sc, sh);
}

// ---------------- launch ----------------

static inline char* bump(char*& p, size_t bytes) {
    char* r = p;
    p += (bytes + 255) & ~(size_t)255;
    return r;
}

extern "C" void kernel_launch(void* const* d_in, const int* in_sizes, int n_in,
                              void* d_out, int out_size, void* d_ws, size_t ws_size,
                              hipStream_t stream) {
    const float* x   = (const float*)d_in[0];
    const int* eic   = (const int*)d_in[1];
    const int* eid   = (const int*)d_in[2];
    const float* W1l = (const float*)d_in[3];
    const float* W1r = (const float*)d_in[4];
    const float* W2l = (const float*)d_in[5];
    const float* W2r = (const float*)d_in[6];
    const float* W3l = (const float*)d_in[7];
    const float* W3r = (const float*)d_in[8];
    const float* W4l = (const float*)d_in[9];
    const float* W4r = (const float*)d_in[10];
    const float* g1 = (const float*)d_in[11];
    const float* b1 = (const float*)d_in[12];
    const float* g2 = (const float*)d_in[13];
    const float* b2 = (const float*)d_in[14];
    const float* g3 = (const float*)d_in[15];
    const float* b3 = (const float*)d_in[16];
    const float* g4 = (const float*)d_in[17];
    const float* b4 = (const float*)d_in[18];
    float* out = (float*)d_out;

    // workspace layout (zero-init region first)
    char* p = (char*)d_ws;
    int*   deg_ic = (int*)  bump(p, NN * 4);
    int*   deg_id = (int*)  bump(p, NN * 4);
    float* stats  = (float*)bump(p, 5 * 16 * 4);   // 5 layers x (sum[8], sumsq[8])
    int*   gcnt   = (int*)  bump(p, 2 * 4);
    size_t zero_bytes = (size_t)(p - (char*)d_ws);
    int*   offs_ic = (int*)  bump(p, NN * 4);
    int*   cur_ic  = (int*)  bump(p, NN * 4);
    int*   offs_id = (int*)  bump(p, NN * 4);
    int*   cur_id  = (int*)  bump(p, NN * 4);
    float* inv_ic  = (float*)bump(p, NN * 4);
    float* inv_id  = (float*)bump(p, NN * 4);
    int*   csr_ic  = (int*)  bump(p, (size_t)EC * 4);
    int*   csr_id  = (int*)  bump(p, (size_t)ED * 4);
    float* r_a     = (float*)bump(p, NN * 8 * 4);
    float* r_b     = (float*)bump(p, NN * 8 * 4);
    (void)ws_size; (void)in_sizes; (void)n_in; (void)out_size;

    hipMemsetAsync(d_ws, 0, zero_bytes, stream);

    count_deg<<<4096, 256, 0, stream>>>(eic, eid, deg_ic, deg_id);
    int nblk = (NN + 255) / 256;
    make_offs<<<nblk, 256, 0, stream>>>(deg_ic, offs_ic, cur_ic, inv_ic, &gcnt[0]);
    make_offs<<<nblk, 256, 0, stream>>>(deg_id, offs_id, cur_id, inv_id, &gcnt[1]);
    fill_csr<<<4096, 256, 0, stream>>>(eic, EC, cur_ic, csr_ic);
    fill_csr<<<2048, 256, 0, stream>>>(eid, ED, cur_id, csr_id);

    int lblk = (NN + 3) / 4;   // one wave per node, 4 waves/block
    // L1: conv1 (x, eic) -> stats0
    sage_layer<5, false><<<lblk, 256, 0, stream>>>(
        x, nullptr, nullptr, nullptr,
        offs_ic, deg_ic, csr_ic, inv_ic, W1l, W1r, r_a, stats + 0);
    // L2: conv4 (eic), input BN1(g1,b1)
    sage_layer<8, true><<<lblk, 256, 0, stream>>>(
        r_a, stats + 0, g1, b1,
        offs_ic, deg_ic, csr_ic, inv_ic, W4l, W4r, r_b, stats + 16);
    // L3: conv2 (eid), input BN2(g2,b2)
    sage_layer<8, true><<<lblk, 256, 0, stream>>>(
        r_b, stats + 16, g2, b2,
        offs_id, deg_id, csr_id, inv_id, W2l, W2r, r_a, stats + 32);
    // L4: conv3 (eic), input BN3(g3,b3)
    sage_layer<8, true><<<lblk, 256, 0, stream>>>(
        r_a, stats + 32, g3, b3,
        offs_ic, deg_ic, csr_ic, inv_ic, W3l, W3r, r_b, stats + 48);
    // L5: conv3 (eic), input BN4(g4,b4)
    sage_layer<8, true><<<lblk, 256, 0, stream>>>(
        r_b, stats + 48, g4, b4,
        offs_ic, deg_ic, csr_ic, inv_ic, W3l, W3r, r_a, stats + 64);
    // final BN4(g4,b4) -> out
    apply_bn_out<<<(NN * 8 + 255) / 256, 256, 0, stream>>>(r_a, stats + 64, g4, b4, out);
}

// Round 2
// 1485.613 us; speedup vs baseline: 2.6948x; 2.6948x over previous
//
#include <hip/hip_runtime.h>

#define NN 100000
#define EC 6400000
#define ED 400000
#define BN_EPS 1e-5f

// ---------------- CSR build ----------------

__global__ void count_deg(const int* __restrict__ eic, const int* __restrict__ eid,
                          int* __restrict__ deg_ic, int* __restrict__ deg_id) {
    int t = blockIdx.x * blockDim.x + threadIdx.x;
    int stride = gridDim.x * blockDim.x;
    for (int e = t; e < EC; e += stride) atomicAdd(&deg_ic[eic[EC + e]], 1);
    for (int e = t; e < ED; e += stride) atomicAdd(&deg_id[eid[ED + e]], 1);
}

// per-wave exclusive scan of degrees + one global-cursor atomic per wave
__global__ void make_offs(const int* __restrict__ deg, int* __restrict__ offs,
                          int* __restrict__ cur, float* __restrict__ inv,
                          int* __restrict__ gcnt) {
    int t = blockIdx.x * blockDim.x + threadIdx.x;
    int lane = threadIdx.x & 63;
    int d = (t < NN) ? deg[t] : 0;
    int x = d;
    #pragma unroll
    for (int s = 1; s < 64; s <<= 1) {
        int y = __shfl_up(x, s);
        if (lane >= s) x += y;
    }
    int total = __shfl(x, 63);           // wave total (inclusive scan at lane 63)
    int base = 0;
    if (lane == 0) base = atomicAdd(gcnt, total);
    base = __shfl(base, 0);
    if (t < NN) {
        int o = base + (x - d);          // exclusive within wave
        offs[t] = o;
        cur[t]  = o;
        inv[t]  = 1.0f / (float)(d > 1 ? d : 1);
    }
}

__global__ void fill_csr(const int* __restrict__ ei, int E,
                         int* __restrict__ cur, int* __restrict__ csr) {
    int t = blockIdx.x * blockDim.x + threadIdx.x;
    int stride = gridDim.x * blockDim.x;
    for (int e = t; e < E; e += stride) {
        int src = ei[e];
        int dst = ei[E + e];
        int p = atomicAdd(&cur[dst], 1);
        csr[p] = src;
    }
}

// ---------------- fused SAGE layer ----------------
// Grid-stride, one wave per node per iteration. Lane = e8*8 + f.
// CSR entries for a node are loaded 64-at-a-time (coalesced) and broadcast
// via shfl, so the 8 hin gathers per chunk are independent (8 outstanding
// loads/wave instead of a csr->hin dependent chain).
// BN stats: register accum across nodes -> LDS -> 16 padded global atomics
// per block (one cache line per feature; was 400K same-line atomics = 1ms).
template<int FIN_, bool APPLY_BN>
__global__ __launch_bounds__(256)
void sage_layer(const float* __restrict__ hin,
                const float* __restrict__ stats_in,   // padded: [f*16]=sum, [(8+f)*16]=sumsq
                const float* __restrict__ gin, const float* __restrict__ bin,
                const int* __restrict__ offs, const int* __restrict__ deg,
                const int* __restrict__ csr, const float* __restrict__ inv,
                const float* __restrict__ Wl, const float* __restrict__ Wr,
                float* __restrict__ hout,
                float* __restrict__ stats_out) {
    __shared__ float bl[16];
    int tid = threadIdx.x;
    if (tid < 16) bl[tid] = 0.f;
    __syncthreads();

    int wave = tid >> 6;
    int lane = tid & 63;
    int e8 = lane >> 3;
    int f  = lane & 7;

    float sc = 1.f, sh = 0.f;
    if constexpr (APPLY_BN) {
        float m = stats_in[f * 16] * (1.0f / NN);
        float v = stats_in[(8 + f) * 16] * (1.0f / NN) - m * m;
        float is = rsqrtf(v + BN_EPS);
        sc = gin[f] * is;
        sh = bin[f] - m * sc;
    }

    const bool actf = (f < FIN_);
    const int W = gridDim.x * 4;
    float acc_r = 0.f, acc_r2 = 0.f;

    for (int i = blockIdx.x * 4 + wave; i < NN; i += W) {
        int d = deg[i];
        int o = offs[i];
        float s = 0.f;
        for (int base = 0; base < d; base += 64) {
            int rem = d - base;
            int c = 0;
            if (lane < rem) c = csr[o + base + lane];
            #pragma unroll
            for (int it = 0; it < 8; ++it) {
                int j = it * 8 + e8;
                int src = __shfl(c, j);
                if ((base + j) < d && actf) {
                    float v = hin[src * FIN_ + f];
                    if constexpr (APPLY_BN) v = fmaf(v, sc, sh);
                    s += v;
                }
            }
        }
        // reduce over the 8 edge slots (lanes differing in bits 3..5)
        s += __shfl_xor(s, 8);
        s += __shfl_xor(s, 16);
        s += __shfl_xor(s, 32);
        float meanf = s * inv[i];

        float hf = 0.f;
        if (actf) {
            hf = hin[i * FIN_ + f];
            if constexpr (APPLY_BN) hf = fmaf(hf, sc, sh);
        }

        // y_f = sum_k mean_k*Wl[f][k] + h_k*Wr[f][k]   (shuffle within 8-lane group)
        float y = 0.f;
        int gbase = lane & ~7;
        #pragma unroll
        for (int k = 0; k < FIN_; ++k) {
            float mk = __shfl(meanf, gbase + k);
            float hk = __shfl(hf, gbase + k);
            y = fmaf(mk, Wl[f * FIN_ + k], y);
            y = fmaf(hk, Wr[f * FIN_ + k], y);
        }
        // row L2 norm over 8 features (lanes differing in bits 0..2)
        float n2 = y * y;
        n2 += __shfl_xor(n2, 1);
        n2 += __shfl_xor(n2, 2);
        n2 += __shfl_xor(n2, 4);
        float z = y / fmaxf(sqrtf(n2), 1e-12f);
        float r = fmaxf(z, 0.f);
        if (e8 == 0) hout[i * 8 + f] = r;
        acc_r  += r;
        acc_r2 += r * r;
    }

    if (e8 == 0) {
        atomicAdd(&bl[f], acc_r);
        atomicAdd(&bl[8 + f], acc_r2);
    }
    __syncthreads();
    if (tid < 16) atomicAdd(&stats_out[tid * 16], bl[tid]);   // padded: 1 line per feature
}

__global__ void apply_bn_out(const float* __restrict__ hin,
                             const float* __restrict__ stats,
                             const float* __restrict__ g, const float* __restrict__ b,
                             float* __restrict__ out) {
    int t = blockIdx.x * blockDim.x + threadIdx.x;
    if (t >= NN * 8) return;
    int f = t & 7;
    float m = stats[f * 16] * (1.0f / NN);
    float v = stats[(8 + f) * 16] * (1.0f / NN) - m * m;
    float sc = g[f] * rsqrtf(v + BN_EPS);
    float sh = b[f] - m * sc;
    out[t] = fmaf(hin[t], sc, sh);
}

// ---------------- launch ----------------

static inline char* bump(char*& p, size_t bytes) {
    char* r = p;
    p += (bytes + 255) & ~(size_t)255;
    return r;
}

extern "C" void kernel_launch(void* const* d_in, const int* in_sizes, int n_in,
                              void* d_out, int out_size, void* d_ws, size_t ws_size,
                              hipStream_t stream) {
    const float* x   = (const float*)d_in[0];
    const int* eic   = (const int*)d_in[1];
    const int* eid   = (const int*)d_in[2];
    const float* W1l = (const float*)d_in[3];
    const float* W1r = (const float*)d_in[4];
    const float* W2l = (const float*)d_in[5];
    const float* W2r = (const float*)d_in[6];
    const float* W3l = (const float*)d_in[7];
    const float* W3r = (const float*)d_in[8];
    const float* W4l = (const float*)d_in[9];
    const float* W4r = (const float*)d_in[10];
    const float* g1 = (const float*)d_in[11];
    const float* b1 = (const float*)d_in[12];
    const float* g2 = (const float*)d_in[13];
    const float* b2 = (const float*)d_in[14];
    const float* g3 = (const float*)d_in[15];
    const float* b3 = (const float*)d_in[16];
    const float* g4 = (const float*)d_in[17];
    const float* b4 = (const float*)d_in[18];
    float* out = (float*)d_out;

    // workspace layout (zero-init region first)
    char* p = (char*)d_ws;
    int*   deg_ic = (int*)  bump(p, NN * 4);
    int*   deg_id = (int*)  bump(p, NN * 4);
    float* stats  = (float*)bump(p, 5 * 256 * 4);  // 5 layers x 16 features x 16-pad
    int*   gcnt   = (int*)  bump(p, 2 * 4);
    size_t zero_bytes = (size_t)(p - (char*)d_ws);
    int*   offs_ic = (int*)  bump(p, NN * 4);
    int*   cur_ic  = (int*)  bump(p, NN * 4);
    int*   offs_id = (int*)  bump(p, NN * 4);
    int*   cur_id  = (int*)  bump(p, NN * 4);
    float* inv_ic  = (float*)bump(p, NN * 4);
    float* inv_id  = (float*)bump(p, NN * 4);
    int*   csr_ic  = (int*)  bump(p, (size_t)EC * 4);
    int*   csr_id  = (int*)  bump(p, (size_t)ED * 4);
    float* r_a     = (float*)bump(p, NN * 8 * 4);
    float* r_b     = (float*)bump(p, NN * 8 * 4);
    (void)ws_size; (void)in_sizes; (void)n_in; (void)out_size;

    hipMemsetAsync(d_ws, 0, zero_bytes, stream);

    count_deg<<<4096, 256, 0, stream>>>(eic, eid, deg_ic, deg_id);
    int nblk = (NN + 255) / 256;
    make_offs<<<nblk, 256, 0, stream>>>(deg_ic, offs_ic, cur_ic, inv_ic, &gcnt[0]);
    make_offs<<<nblk, 256, 0, stream>>>(deg_id, offs_id, cur_id, inv_id, &gcnt[1]);
    fill_csr<<<4096, 256, 0, stream>>>(eic, EC, cur_ic, csr_ic);
    fill_csr<<<2048, 256, 0, stream>>>(eid, ED, cur_id, csr_id);

    const int LB = 2048;   // 8192 waves = full residency; grid-stride over nodes
    // L1: conv1 (x, eic) -> stats0
    sage_layer<5, false><<<LB, 256, 0, stream>>>(
        x, nullptr, nullptr, nullptr,
        offs_ic, deg_ic, csr_ic, inv_ic, W1l, W1r, r_a, stats + 0);
    // L2: conv4 (eic), input BN1(g1,b1)
    sage_layer<8, true><<<LB, 256, 0, stream>>>(
        r_a, stats + 0, g1, b1,
        offs_ic, deg_ic, csr_ic, inv_ic, W4l, W4r, r_b, stats + 256);
    // L3: conv2 (eid), input BN2(g2,b2)
    sage_layer<8, true><<<LB, 256, 0, stream>>>(
        r_b, stats + 256, g2, b2,
        offs_id, deg_id, csr_id, inv_id, W2l, W2r, r_a, stats + 512);
    // L4: conv3 (eic), input BN3(g3,b3)
    sage_layer<8, true><<<LB, 256, 0, stream>>>(
        r_a, stats + 512, g3, b3,
        offs_ic, deg_ic, csr_ic, inv_ic, W3l, W3r, r_b, stats + 768);
    // L5: conv3 (eic), input BN4(g4,b4)
    sage_layer<8, true><<<LB, 256, 0, stream>>>(
        r_b, stats + 768, g4, b4,
        offs_ic, deg_ic, csr_ic, inv_ic, W3l, W3r, r_a, stats + 1024);
    // final BN4(g4,b4) -> out
    apply_bn_out<<<(NN * 8 + 255) / 256, 256, 0, stream>>>(r_a, stats + 1024, g4, b4, out);
}

// Round 3
// 799.309 us; speedup vs baseline: 5.0087x; 1.8586x over previous
//
#include <hip/hip_runtime.h>

#define NN 100000
#define EC 6400000
#define ED 400000
#define BN_EPS 1e-5f
#define NBK ((NN + 127) >> 7)   // 782 node buckets of 128 nodes
#define NCH 512                 // edge chunks (also scatter grid size)

// ---------------- bucket-sort CSR build ----------------
// csr[p]=src with random p was 15x write-amplified (386MB HBM writes, R2).
// Two-level: group edges by 128-node bucket (compact per-(block,bucket)
// write regions), then build exact CSR per bucket in an L2-resident 32KB
// region. deg/offs/inv derived from histograms (count_deg/make_offs gone).

__global__ __launch_bounds__(256)
void hist_pass(const int* __restrict__ ei, int E, int* __restrict__ bhist) {
    __shared__ int h[NBK];
    for (int i = threadIdx.x; i < NBK; i += 256) h[i] = 0;
    __syncthreads();
    int k = blockIdx.x;
    int chunk = (E + NCH - 1) / NCH;
    int beg = k * chunk, end = min(E, beg + chunk);
    for (int e = beg + threadIdx.x; e < end; e += 256)
        atomicAdd(&h[ei[E + e] >> 7], 1);
    __syncthreads();
    for (int i = threadIdx.x; i < NBK; i += 256) bhist[i * NCH + k] = h[i];
}

// per-bucket exclusive scan over its NCH chunk counts (in place) + total
__global__ __launch_bounds__(256)
void row_scan(int* __restrict__ bhist, int* __restrict__ total) {
    int b = blockIdx.x;
    int* row = bhist + b * NCH;
    __shared__ int wsum[4];
    __shared__ int carry;
    if (threadIdx.x == 0) carry = 0;
    __syncthreads();
    int lane = threadIdx.x & 63, w = threadIdx.x >> 6;
    for (int s = 0; s < NCH; s += 256) {
        int v = row[s + threadIdx.x];
        int x = v;
        #pragma unroll
        for (int sh = 1; sh < 64; sh <<= 1) { int y = __shfl_up(x, sh); if (lane >= sh) x += y; }
        if (lane == 63) wsum[w] = x;
        __syncthreads();
        int wb = 0;
        #pragma unroll
        for (int j = 0; j < 4; ++j) if (j < w) wb += wsum[j];
        int all = wsum[0] + wsum[1] + wsum[2] + wsum[3];
        row[s + threadIdx.x] = carry + wb + x - v;   // exclusive
        __syncthreads();
        if (threadIdx.x == 0) carry += all;
        __syncthreads();
    }
    if (threadIdx.x == 0) total[b] = carry;
}

// exclusive scan over NBK bucket totals -> bucket edge bases
__global__ void bucket_base(const int* __restrict__ total, int* __restrict__ bbase) {
    __shared__ int wsum[4];
    __shared__ int carry;
    if (threadIdx.x == 0) carry = 0;
    __syncthreads();
    int lane = threadIdx.x & 63, w = threadIdx.x >> 6;
    for (int s = 0; s < NBK; s += 256) {
        int idx = s + threadIdx.x;
        int v = (idx < NBK) ? total[idx] : 0;
        int x = v;
        #pragma unroll
        for (int sh = 1; sh < 64; sh <<= 1) { int y = __shfl_up(x, sh); if (lane >= sh) x += y; }
        if (lane == 63) wsum[w] = x;
        __syncthreads();
        int wb = 0;
        #pragma unroll
        for (int j = 0; j < 4; ++j) if (j < w) wb += wsum[j];
        int all = wsum[0] + wsum[1] + wsum[2] + wsum[3];
        if (idx < NBK) bbase[idx] = carry + wb + x - v;
        __syncthreads();
        if (threadIdx.x == 0) carry += all;
        __syncthreads();
    }
}

// scatter edges into bucket-grouped order, packed (src:17 | ldst<<17)
__global__ __launch_bounds__(256)
void scatter_pairs(const int* __restrict__ ei, int E,
                   const int* __restrict__ bhist, const int* __restrict__ bbase,
                   unsigned int* __restrict__ packed) {
    __shared__ int cur[NBK];
    int k = blockIdx.x;
    for (int b = threadIdx.x; b < NBK; b += 256)
        cur[b] = bbase[b] + bhist[b * NCH + k];
    __syncthreads();
    int chunk = (E + NCH - 1) / NCH;
    int beg = k * chunk, end = min(E, beg + chunk);
    for (int e = beg + threadIdx.x; e < end; e += 256) {
        int src = ei[e], dst = ei[E + e];
        int b = dst >> 7;
        int p = atomicAdd(&cur[b], 1);
        packed[p] = (unsigned)src | ((unsigned)(dst & 127) << 17);
    }
}

// one block per bucket: LDS hist + scan -> deg/offs/inv + exact CSR placement
__global__ __launch_bounds__(256)
void bucket_csr(const unsigned int* __restrict__ packed,
                const int* __restrict__ bbase, const int* __restrict__ total,
                int* __restrict__ csr, int* __restrict__ offs, int* __restrict__ deg,
                float* __restrict__ inv) {
    int b = blockIdx.x;
    int ebeg = bbase[b], ecnt = total[b];
    int node0 = b << 7;
    int nn = min(128, NN - node0);
    __shared__ int h[128];
    __shared__ int loff[128];
    __shared__ int ws2[2];
    if (threadIdx.x < 128) h[threadIdx.x] = 0;
    __syncthreads();
    for (int e = threadIdx.x; e < ecnt; e += 256)
        atomicAdd(&h[packed[ebeg + e] >> 17], 1);
    __syncthreads();
    if (threadIdx.x < 128) {
        int lane = threadIdx.x & 63, w = threadIdx.x >> 6;
        int v = h[threadIdx.x];
        int x = v;
        #pragma unroll
        for (int sh = 1; sh < 64; sh <<= 1) { int y = __shfl_up(x, sh); if (lane >= sh) x += y; }
        if (lane == 63) ws2[w] = x;
        loff[threadIdx.x] = x - v;           // wave-exclusive
    }
    __syncthreads();
    if (threadIdx.x < 128) {
        int w = threadIdx.x >> 6;
        int excl = loff[threadIdx.x] + (w ? ws2[0] : 0);
        loff[threadIdx.x] = excl;
        if (threadIdx.x < nn) {
            int node = node0 + threadIdx.x;
            int d = h[threadIdx.x];
            offs[node] = ebeg + excl;
            deg[node]  = d;
            inv[node]  = 1.0f / (float)(d > 1 ? d : 1);
        }
    }
    __syncthreads();
    for (int e = threadIdx.x; e < ecnt; e += 256) {
        unsigned u = packed[ebeg + e];
        int p = atomicAdd(&loff[u >> 17], 1);
        csr[ebeg + p] = (int)(u & 0x1FFFF);
    }
}

// ---------------- fused SAGE layer (unchanged from R2) ----------------
template<int FIN_, bool APPLY_BN>
__global__ __launch_bounds__(256)
void sage_layer(const float* __restrict__ hin,
                const float* __restrict__ stats_in,   // padded: [f*16]=sum, [(8+f)*16]=sumsq
                const float* __restrict__ gin, const float* __restrict__ bin,
                const int* __restrict__ offs, const int* __restrict__ deg,
                const int* __restrict__ csr, const float* __restrict__ inv,
                const float* __restrict__ Wl, const float* __restrict__ Wr,
                float* __restrict__ hout,
                float* __restrict__ stats_out) {
    __shared__ float bl[16];
    int tid = threadIdx.x;
    if (tid < 16) bl[tid] = 0.f;
    __syncthreads();

    int wave = tid >> 6;
    int lane = tid & 63;
    int e8 = lane >> 3;
    int f  = lane & 7;

    float sc = 1.f, sh = 0.f;
    if constexpr (APPLY_BN) {
        float m = stats_in[f * 16] * (1.0f / NN);
        float v = stats_in[(8 + f) * 16] * (1.0f / NN) - m * m;
        float is = rsqrtf(v + BN_EPS);
        sc = gin[f] * is;
        sh = bin[f] - m * sc;
    }

    const bool actf = (f < FIN_);
    const int W = gridDim.x * 4;
    float acc_r = 0.f, acc_r2 = 0.f;

    for (int i = blockIdx.x * 4 + wave; i < NN; i += W) {
        int d = deg[i];
        int o = offs[i];
        float s = 0.f;
        for (int base = 0; base < d; base += 64) {
            int rem = d - base;
            int c = 0;
            if (lane < rem) c = csr[o + base + lane];
            #pragma unroll
            for (int it = 0; it < 8; ++it) {
                int j = it * 8 + e8;
                int src = __shfl(c, j);
                if ((base + j) < d && actf) {
                    float v = hin[src * FIN_ + f];
                    if constexpr (APPLY_BN) v = fmaf(v, sc, sh);
                    s += v;
                }
            }
        }
        s += __shfl_xor(s, 8);
        s += __shfl_xor(s, 16);
        s += __shfl_xor(s, 32);
        float meanf = s * inv[i];

        float hf = 0.f;
        if (actf) {
            hf = hin[i * FIN_ + f];
            if constexpr (APPLY_BN) hf = fmaf(hf, sc, sh);
        }

        float y = 0.f;
        int gbase = lane & ~7;
        #pragma unroll
        for (int k = 0; k < FIN_; ++k) {
            float mk = __shfl(meanf, gbase + k);
            float hk = __shfl(hf, gbase + k);
            y = fmaf(mk, Wl[f * FIN_ + k], y);
            y = fmaf(hk, Wr[f * FIN_ + k], y);
        }
        float n2 = y * y;
        n2 += __shfl_xor(n2, 1);
        n2 += __shfl_xor(n2, 2);
        n2 += __shfl_xor(n2, 4);
        float z = y / fmaxf(sqrtf(n2), 1e-12f);
        float r = fmaxf(z, 0.f);
        if (e8 == 0) hout[i * 8 + f] = r;
        acc_r  += r;
        acc_r2 += r * r;
    }

    if (e8 == 0) {
        atomicAdd(&bl[f], acc_r);
        atomicAdd(&bl[8 + f], acc_r2);
    }
    __syncthreads();
    if (tid < 16) atomicAdd(&stats_out[tid * 16], bl[tid]);   // 1 cache line per feature
}

__global__ void apply_bn_out(const float* __restrict__ hin,
                             const float* __restrict__ stats,
                             const float* __restrict__ g, const float* __restrict__ b,
                             float* __restrict__ out) {
    int t = blockIdx.x * blockDim.x + threadIdx.x;
    if (t >= NN * 8) return;
    int f = t & 7;
    float m = stats[f * 16] * (1.0f / NN);
    float v = stats[(8 + f) * 16] * (1.0f / NN) - m * m;
    float sc = g[f] * rsqrtf(v + BN_EPS);
    float sh = b[f] - m * sc;
    out[t] = fmaf(hin[t], sc, sh);
}

// ---------------- launch ----------------

static inline char* bump(char*& p, size_t bytes) {
    char* r = p;
    p += (bytes + 255) & ~(size_t)255;
    return r;
}

extern "C" void kernel_launch(void* const* d_in, const int* in_sizes, int n_in,
                              void* d_out, int out_size, void* d_ws, size_t ws_size,
                              hipStream_t stream) {
    const float* x   = (const float*)d_in[0];
    const int* eic   = (const int*)d_in[1];
    const int* eid   = (const int*)d_in[2];
    const float* W1l = (const float*)d_in[3];
    const float* W1r = (const float*)d_in[4];
    const float* W2l = (const float*)d_in[5];
    const float* W2r = (const float*)d_in[6];
    const float* W3l = (const float*)d_in[7];
    const float* W3r = (const float*)d_in[8];
    const float* W4l = (const float*)d_in[9];
    const float* W4r = (const float*)d_in[10];
    const float* g1 = (const float*)d_in[11];
    const float* b1 = (const float*)d_in[12];
    const float* g2 = (const float*)d_in[13];
    const float* b2 = (const float*)d_in[14];
    const float* g3 = (const float*)d_in[15];
    const float* b3 = (const float*)d_in[16];
    const float* g4 = (const float*)d_in[17];
    const float* b4 = (const float*)d_in[18];
    float* out = (float*)d_out;

    // workspace layout
    char* p = (char*)d_ws;
    float* stats   = (float*)bump(p, 5 * 256 * 4);       // zero region (only this)
    size_t zero_bytes = (size_t)(p - (char*)d_ws);
    int*   offs_c  = (int*)  bump(p, NN * 4);
    int*   deg_c   = (int*)  bump(p, NN * 4);
    float* inv_c   = (float*)bump(p, NN * 4);
    int*   offs_d  = (int*)  bump(p, NN * 4);
    int*   deg_d   = (int*)  bump(p, NN * 4);
    float* inv_d   = (float*)bump(p, NN * 4);
    int*   bhist_c = (int*)  bump(p, (size_t)NBK * NCH * 4);
    int*   bhist_d = (int*)  bump(p, (size_t)NBK * NCH * 4);
    int*   total_c = (int*)  bump(p, NBK * 4);
    int*   bbase_c = (int*)  bump(p, NBK * 4);
    int*   total_d = (int*)  bump(p, NBK * 4);
    int*   bbase_d = (int*)  bump(p, NBK * 4);
    int*   csr_c   = (int*)  bump(p, (size_t)EC * 4);
    int*   csr_d   = (int*)  bump(p, (size_t)ED * 4);
    unsigned int* packed_d = (unsigned int*)bump(p, (size_t)ED * 4);
    // packed_c is dead after bucket_csr; overlay r_a/r_b on its region
    char* pc = p;
    unsigned int* packed_c = (unsigned int*)bump(p, (size_t)EC * 4);
    char* pr = pc;
    float* r_a = (float*)bump(pr, NN * 8 * 4);
    float* r_b = (float*)bump(pr, NN * 8 * 4);
    (void)ws_size; (void)in_sizes; (void)n_in; (void)out_size;

    hipMemsetAsync(d_ws, 0, zero_bytes, stream);

    hist_pass<<<NCH, 256, 0, stream>>>(eic, EC, bhist_c);
    hist_pass<<<NCH, 256, 0, stream>>>(eid, ED, bhist_d);
    row_scan<<<NBK, 256, 0, stream>>>(bhist_c, total_c);
    row_scan<<<NBK, 256, 0, stream>>>(bhist_d, total_d);
    bucket_base<<<1, 256, 0, stream>>>(total_c, bbase_c);
    bucket_base<<<1, 256, 0, stream>>>(total_d, bbase_d);
    scatter_pairs<<<NCH, 256, 0, stream>>>(eic, EC, bhist_c, bbase_c, packed_c);
    scatter_pairs<<<NCH, 256, 0, stream>>>(eid, ED, bhist_d, bbase_d, packed_d);
    bucket_csr<<<NBK, 256, 0, stream>>>(packed_c, bbase_c, total_c, csr_c, offs_c, deg_c, inv_c);
    bucket_csr<<<NBK, 256, 0, stream>>>(packed_d, bbase_d, total_d, csr_d, offs_d, deg_d, inv_d);

    const int LB = 2048;   // 8192 waves; grid-stride over nodes
    sage_layer<5, false><<<LB, 256, 0, stream>>>(
        x, nullptr, nullptr, nullptr,
        offs_c, deg_c, csr_c, inv_c, W1l, W1r, r_a, stats + 0);
    sage_layer<8, true><<<LB, 256, 0, stream>>>(
        r_a, stats + 0, g1, b1,
        offs_c, deg_c, csr_c, inv_c, W4l, W4r, r_b, stats + 256);
    sage_layer<8, true><<<LB, 256, 0, stream>>>(
        r_b, stats + 256, g2, b2,
        offs_d, deg_d, csr_d, inv_d, W2l, W2r, r_a, stats + 512);
    sage_layer<8, true><<<LB, 256, 0, stream>>>(
        r_a, stats + 512, g3, b3,
        offs_c, deg_c, csr_c, inv_c, W3l, W3r, r_b, stats + 768);
    sage_layer<8, true><<<LB, 256, 0, stream>>>(
        r_b, stats + 768, g4, b4,
        offs_c, deg_c, csr_c, inv_c, W3l, W3r, r_a, stats + 1024);
    apply_bn_out<<<(NN * 8 + 255) / 256, 256, 0, stream>>>(r_a, stats + 1024, g4, b4, out);
}